// Round 4
// baseline (369.320 us; speedup 1.0000x reference)
//
#include <hip/hip_runtime.h>
#include <math.h>

#define NUM_GROUPS 100
#define GROUP_SIZE 100
#define TOTAL_ROWS 10000
#define NUM_CLASSES 1000
#define BATCH 4096
#define SPB 2                      // samples per gather block
#define GATHER_BLOCKS (BATCH / SPB)
#define CHUNK 128                  // classes per prep block (power of 2)

// bf16 helpers: pack with RTNE, unpack via shift (bf16->fp32 is exact)
__device__ __forceinline__ unsigned int f2bf(float f) {
    unsigned int u = __float_as_uint(f);
    return (u + 0x7FFFu + ((u >> 16) & 1u)) >> 16;
}
__device__ __forceinline__ float bflo(unsigned int p) { return __uint_as_float(p << 16); }
__device__ __forceinline__ float bfhi(unsigned int p) { return __uint_as_float(p & 0xFFFF0000u); }

// ---------------------------------------------------------------------------
__global__ __launch_bounds__(256)
void k_init_base(const float* __restrict__ bias, float* __restrict__ base) {
    int c = blockIdx.x * 256 + threadIdx.x;
    if (c < NUM_CLASSES) base[c] = bias[c];
}

// ---------------------------------------------------------------------------
// k_prep: fused corr + bf16 convert. Block = (group g, 128-class chunk).
// Stage 100x128 fp32 slab in LDS (one coalesced read of W -> 40 MB total),
// then (a) per-class max & sum-exp from LDS -> atomicAdd(-(M+logS)) into
// base, (b) pack the slab to bf16 pairs -> Wh table. W is read exactly once.
// LDS: 50 KB slab + 1 KB scratch -> 3 blocks/CU; grid 800 blocks.
// ---------------------------------------------------------------------------
__global__ __launch_bounds__(256)
void k_prep(const float* __restrict__ W, float* __restrict__ base,
            unsigned int* __restrict__ Wh) {
    __shared__ float slab[GROUP_SIZE * CHUNK];    // 51200 B
    __shared__ float sh[2][CHUNK];

    const int g   = blockIdx.x;
    const int cy  = blockIdx.y;                   // 0..7
    const int tid = threadIdx.x;

    // ---- stage slab: 12800 = 50 * 256 iterations, coalesced 512 B rows ----
    #pragma unroll 5
    for (int k = 0; k < 50; ++k) {
        int i  = tid + k * 256;
        int r  = i >> 7;
        int cl = i & 127;
        int c  = cy * CHUNK + cl;
        float v = (c < NUM_CLASSES)
                ? W[(size_t)(g * GROUP_SIZE + r) * NUM_CLASSES + c]
                : -1e30f;
        slab[i] = v;
    }
    __syncthreads();

    // ---- per-class max (two 50-row halves) ----
    const int q  = tid >> 7;                      // 0,1
    const int cl = tid & 127;
    const int c  = cy * CHUNK + cl;

    float m = -INFINITY;
    #pragma unroll 10
    for (int r = q * 50; r < q * 50 + 50; ++r)
        m = fmaxf(m, slab[r * CHUNK + cl]);
    sh[q][cl] = m;
    __syncthreads();
    const float M = fmaxf(sh[0][cl], sh[1][cl]);
    __syncthreads();

    // ---- per-class sum of exp ----
    float s = 0.0f;
    #pragma unroll 10
    for (int r = q * 50; r < q * 50 + 50; ++r)
        s += __expf(slab[r * CHUNK + cl] - M);
    sh[q][cl] = s;
    __syncthreads();
    if (q == 0 && c < NUM_CLASSES) {
        float S = sh[0][cl] + sh[1][cl];
        atomicAdd(base + c, -(M + __logf(S)));
    }

    // ---- bf16 pack: 6400 = 25 * 256 pair-iterations ----
    #pragma unroll 5
    for (int k = 0; k < 25; ++k) {
        int i = tid + k * 256;
        int r = i >> 6;
        int p = i & 63;
        int u = cy * 64 + p;                      // uint (bf16-pair) index in row
        if (u < NUM_CLASSES / 2) {
            float f0 = slab[r * CHUNK + 2 * p];
            float f1 = slab[r * CHUNK + 2 * p + 1];
            Wh[(size_t)(g * GROUP_SIZE + r) * (NUM_CLASSES / 2) + u] =
                f2bf(f0) | (f2bf(f1) << 16);
        }
    }
}

// ---------------------------------------------------------------------------
// k_gather: fused index-extract + gather + softmax. 2048 blocks x 2 samples.
//  Phase 0: scan the block's own 2 x-rows (80 KB HBM) -> idx_s[2][100].
//           Overlaps other blocks' L3 gathers across the 32 waves/CU.
//  Phase 1: thread t serves sample s=t>>7, class-oct j=t&127 (125 active);
//           per group one uint4 load (8 bf16 = 2 KB/wave granule), unroll 4.
//           Waves are sample-uniform -> readfirstlane scalar addressing.
//  Phase 2: per-sample softmax across 2 waves (shuffle + LDS), 2x float4 out.
// ---------------------------------------------------------------------------
__global__ __launch_bounds__(256)
void k_gather(const float* __restrict__ x, const uint4* __restrict__ Wh4,
              const float* __restrict__ base, float* __restrict__ out) {
    __shared__ int   idx_s[SPB * NUM_GROUPS];
    __shared__ float red[4];
    __shared__ float red2[4];

    const int b0  = blockIdx.x * SPB;
    const int tid = threadIdx.x;

    // ---- Phase 0: scan x rows of the SPB samples (5000 float4) ----
    const float4* x4 = (const float4*)(x + (size_t)b0 * TOTAL_ROWS);
    for (int k0 = 0; k0 < 20; k0 += 4) {
        float4 v[4];
        int    ii[4];
        #pragma unroll
        for (int u = 0; u < 4; ++u) {
            ii[u] = tid + (k0 + u) * 256;
            v[u] = (ii[u] < SPB * 2500) ? x4[ii[u]]
                                        : make_float4(0.f, 0.f, 0.f, 0.f);
        }
        #pragma unroll
        for (int u = 0; u < 4; ++u) {
            float4 vv = v[u];
            if (vv.x > 0.5f || vv.y > 0.5f || vv.z > 0.5f || vv.w > 0.5f) {
                int i  = ii[u];
                int s  = i / 2500;
                int r4 = i - s * 2500;
                int g  = r4 / 25;                 // float4 never crosses group
                int j  = r4 * 4;
                int val = vv.x > 0.5f ? j
                        : (vv.y > 0.5f ? j + 1 : (vv.z > 0.5f ? j + 2 : j + 3));
                idx_s[s * NUM_GROUPS + g] = val;
            }
        }
    }
    __syncthreads();

    // ---- Phase 1: gather-accumulate, 8 classes/thread ----
    const int  s    = tid >> 7;                   // sample within block
    const int  j    = tid & 127;                  // class-oct
    const bool act  = (j < 125);
    const int  jc   = act ? j : 124;              // clamped
    const int  lane = tid & 63;
    const int  wv   = tid >> 6;

    float acc[8];
    #pragma unroll
    for (int k = 0; k < 8; ++k) acc[k] = 0.0f;

    const int* myidx = idx_s + s * NUM_GROUPS;
    for (int g = 0; g < NUM_GROUPS; g += 4) {
        uint4 w[4];
        #pragma unroll
        for (int u = 0; u < 4; ++u) {
            int r = __builtin_amdgcn_readfirstlane(myidx[g + u]);
            w[u] = Wh4[(size_t)r * 125 + jc];
        }
        #pragma unroll
        for (int u = 0; u < 4; ++u) {
            acc[0] += bflo(w[u].x); acc[1] += bfhi(w[u].x);
            acc[2] += bflo(w[u].y); acc[3] += bfhi(w[u].y);
            acc[4] += bflo(w[u].z); acc[5] += bfhi(w[u].z);
            acc[6] += bflo(w[u].w); acc[7] += bfhi(w[u].w);
        }
    }

    const float4 bb0 = *(const float4*)(base + jc * 8);
    const float4 bb1 = *(const float4*)(base + jc * 8 + 4);
    acc[0] += bb0.x; acc[1] += bb0.y; acc[2] += bb0.z; acc[3] += bb0.w;
    acc[4] += bb1.x; acc[5] += bb1.y; acc[6] += bb1.z; acc[7] += bb1.w;

    // ---- Phase 2a: per-sample block max (2 waves per sample) ----
    float m = -INFINITY;
    if (act) {
        #pragma unroll
        for (int k = 0; k < 8; ++k) m = fmaxf(m, acc[k]);
    }
    #pragma unroll
    for (int off = 32; off > 0; off >>= 1)
        m = fmaxf(m, __shfl_down(m, off, 64));
    if (lane == 0) red[wv] = m;
    __syncthreads();
    const float M = fmaxf(red[2 * s], red[2 * s + 1]);

    // ---- Phase 2b: exp + per-sample sum ----
    float e[8];
    float ls = 0.0f;
    #pragma unroll
    for (int k = 0; k < 8; ++k) {
        e[k] = __expf(acc[k] - M);
        ls += e[k];
    }
    if (!act) ls = 0.0f;
    #pragma unroll
    for (int off = 32; off > 0; off >>= 1)
        ls += __shfl_down(ls, off, 64);
    if (lane == 0) red2[wv] = ls;
    __syncthreads();
    const float inv = 1.0f / (red2[2 * s] + red2[2 * s + 1]);

    if (act) {
        float* op = out + (size_t)(b0 + s) * NUM_CLASSES + j * 8;
        *(float4*)(op)     = make_float4(e[0] * inv, e[1] * inv, e[2] * inv, e[3] * inv);
        *(float4*)(op + 4) = make_float4(e[4] * inv, e[5] * inv, e[6] * inv, e[7] * inv);
    }
}

extern "C" void kernel_launch(void* const* d_in, const int* in_sizes, int n_in,
                              void* d_out, int out_size, void* d_ws, size_t ws_size,
                              hipStream_t stream) {
    const float* x    = (const float*)d_in[0];  // (4096, 10000)
    const float* W    = (const float*)d_in[1];  // (10000, 1000)
    const float* bias = (const float*)d_in[2];  // (1000,)
    float* out = (float*)d_out;                 // (4096, 1000)

    char* ws = (char*)d_ws;
    float*        base = (float*)ws;                    // 4 KB
    unsigned int* Wh   = (unsigned int*)(ws + 4096);    // 10000*500*4 = 20 MB

    k_init_base<<<4, 256, 0, stream>>>(bias, base);
    dim3 gp(NUM_GROUPS, 8);
    k_prep<<<gp, 256, 0, stream>>>(W, base, Wh);
    k_gather<<<GATHER_BLOCKS, 256, 0, stream>>>(x, (const uint4*)Wh, base, out);
}